// Round 12
// baseline (120.026 us; speedup 1.0000x reference)
//
#include <hip/hip_runtime.h>
#include <math.h>
#include <float.h>

#define B 32
#define N 2048
#define EPS 1e-6f
#define GD 16
#define NC (GD * GD)          // 256 cells per (set,batch)

// ws layout (floats):
//   bounds : 64*4                     @ 0
//   start  : 64*257 ints              @ 256
//   sorted : 64*2048 float2           @ 16704
//   partial: 512                      @ 16704 + 262144

// Build: one block per (set,b). Counting-sort 2048 points into a 16x16 grid
// over the set's own bbox. All LDS-local, deterministic counts/offsets;
// intra-cell order is atomic-rank (order-independent under min).
__global__ __launch_bounds__(256) void build_grid_kernel(
    const float* __restrict__ pred, const float* __restrict__ target,
    float* __restrict__ bounds, int* __restrict__ start,
    float2* __restrict__ sorted) {
  const int sb = blockIdx.x;       // 0..63 : set*32 + b   (set0=pred, set1=target)
  const int set = sb >> 5, b = sb & 31;
  const float2* pts = (const float2*)(set ? target : pred) + (size_t)b * N;

  __shared__ float wmin_x[4], wmax_x[4], wmin_y[4], wmax_y[4];
  __shared__ float bnd[4];
  __shared__ int counts[NC];
  __shared__ int offs[NC + 1];
  __shared__ int cursor[NC];
  __shared__ int wtot[4];

  float2 p[8];
#pragma unroll
  for (int k = 0; k < 8; ++k) p[k] = pts[k * 256 + threadIdx.x];

  float mnx = FLT_MAX, mxx = -FLT_MAX, mny = FLT_MAX, mxy = -FLT_MAX;
#pragma unroll
  for (int k = 0; k < 8; ++k) {
    mnx = fminf(mnx, p[k].x); mxx = fmaxf(mxx, p[k].x);
    mny = fminf(mny, p[k].y); mxy = fmaxf(mxy, p[k].y);
  }
#pragma unroll
  for (int off = 32; off > 0; off >>= 1) {
    mnx = fminf(mnx, __shfl_xor(mnx, off, 64));
    mxx = fmaxf(mxx, __shfl_xor(mxx, off, 64));
    mny = fminf(mny, __shfl_xor(mny, off, 64));
    mxy = fmaxf(mxy, __shfl_xor(mxy, off, 64));
  }
  const int w = threadIdx.x >> 6, lane = threadIdx.x & 63;
  if (lane == 0) { wmin_x[w] = mnx; wmax_x[w] = mxx; wmin_y[w] = mny; wmax_y[w] = mxy; }
  counts[threadIdx.x] = 0;
  __syncthreads();
  if (threadIdx.x == 0) {
    bnd[0] = fminf(fminf(wmin_x[0], wmin_x[1]), fminf(wmin_x[2], wmin_x[3]));
    bnd[1] = fmaxf(fmaxf(wmax_x[0], wmax_x[1]), fmaxf(wmax_x[2], wmax_x[3]));
    bnd[2] = fminf(fminf(wmin_y[0], wmin_y[1]), fminf(wmin_y[2], wmin_y[3]));
    bnd[3] = fmaxf(fmaxf(wmax_y[0], wmax_y[1]), fmaxf(wmax_y[2], wmax_y[3]));
    bounds[sb * 4 + 0] = bnd[0]; bounds[sb * 4 + 1] = bnd[1];
    bounds[sb * 4 + 2] = bnd[2]; bounds[sb * 4 + 3] = bnd[3];
  }
  __syncthreads();

  const float bx0 = bnd[0], by0 = bnd[2];
  const float hx = fmaxf((bnd[1] - bnd[0]) * (1.f / GD), 1e-6f);
  const float hy = fmaxf((bnd[3] - bnd[2]) * (1.f / GD), 1e-6f);
  const float ihx = 1.f / hx, ihy = 1.f / hy;

  int cell[8];
#pragma unroll
  for (int k = 0; k < 8; ++k) {
    int cx = min(max((int)floorf((p[k].x - bx0) * ihx), 0), GD - 1);
    int cy = min(max((int)floorf((p[k].y - by0) * ihy), 0), GD - 1);
    cell[k] = cy * GD + cx;
    atomicAdd(&counts[cell[k]], 1);
  }
  __syncthreads();

  // exclusive prefix over 256 cells: wave-scan + cross-wave offsets
  int v = counts[threadIdx.x];
  for (int d = 1; d < 64; d <<= 1) {
    int t = __shfl_up(v, d, 64);
    if (lane >= d) v += t;
  }
  if (lane == 63) wtot[w] = v;
  __syncthreads();
  int add = 0;
  for (int i = 0; i < w; ++i) add += wtot[i];
  offs[threadIdx.x + 1] = v + add;
  if (threadIdx.x == 0) offs[0] = 0;
  __syncthreads();
  cursor[threadIdx.x] = offs[threadIdx.x];
  __syncthreads();

#pragma unroll
  for (int k = 0; k < 8; ++k) {
    const int slot = atomicAdd(&cursor[cell[k]], 1);
    sorted[(size_t)sb * N + slot] = p[k];
  }
  start[sb * (NC + 1) + threadIdx.x] = offs[threadIdx.x];
  if (threadIdx.x == 255) start[sb * (NC + 1) + NC] = offs[NC];
}

// Query: 1 query/thread; ring expansion over the REF set's grid.
// Stop after ring k-1 if m <= ((k-1)*hmin)^2 (cells at Chebyshev>=k are
// >= (k-1)*hmin away; valid for clamped edge cells / out-of-grid queries).
__global__ __launch_bounds__(256) void query_kernel(
    const float* __restrict__ pred, const float* __restrict__ target,
    const float* __restrict__ bounds, const int* __restrict__ start,
    const float2* __restrict__ sorted, float* __restrict__ partial) {
  const int blk = blockIdx.x;      // 0..511
  const int db = blk >> 3;         // 0..63
  const int qc = blk & 7;
  const int dir = db >> 5, b = db & 31;

  const float2* q = (const float2*)(dir ? target : pred) + (size_t)b * N;
  const int refsb = (dir ? 0 : 32) + b;   // dir0 refs=target(set1), dir1 refs=pred(set0)

  const float bx0 = bounds[refsb * 4 + 0], bx1 = bounds[refsb * 4 + 1];
  const float by0 = bounds[refsb * 4 + 2], by1 = bounds[refsb * 4 + 3];
  const float hx = fmaxf((bx1 - bx0) * (1.f / GD), 1e-6f);
  const float hy = fmaxf((by1 - by0) * (1.f / GD), 1e-6f);
  const float ihx = 1.f / hx, ihy = 1.f / hy;
  const float hmin = fminf(hx, hy);
  const int soff = refsb * (NC + 1);
  const size_t pb = (size_t)refsb * N;

  const float2 qp = q[qc * 256 + threadIdx.x];
  const int ci = min(max((int)floorf((qp.x - bx0) * ihx), 0), GD - 1);
  const int cj = min(max((int)floorf((qp.y - by0) * ihy), 0), GD - 1);

  float m = FLT_MAX;
  // ring 0
  {
    const int cell = cj * GD + ci;
    const int e0 = start[soff + cell + 1];
    for (int t = start[soff + cell]; t < e0; ++t) {
      const float2 pp = sorted[pb + t];
      const float dx = qp.x - pp.x, dy = qp.y - pp.y;
      m = fminf(m, fmaf(dx, dx, dy * dy));
    }
  }
  for (int k = 1; k < 2 * GD; ++k) {
    const float lb = (float)(k - 1) * hmin;
    if (m <= lb * lb) break;
    const bool top = (cj - k >= 0), bot = (cj + k <= GD - 1);
    const bool lef = (ci - k >= 0), rig = (ci + k <= GD - 1);
    if (!top && !bot && !lef && !rig) break;   // grid exhausted
    const int i0 = max(ci - k, 0), i1 = min(ci + k, GD - 1);
    if (top) {
      const int rowb = soff + (cj - k) * GD;
      for (int i = i0; i <= i1; ++i) {
        const int e0 = start[rowb + i + 1];
        for (int t = start[rowb + i]; t < e0; ++t) {
          const float2 pp = sorted[pb + t];
          const float dx = qp.x - pp.x, dy = qp.y - pp.y;
          m = fminf(m, fmaf(dx, dx, dy * dy));
        }
      }
    }
    if (bot) {
      const int rowb = soff + (cj + k) * GD;
      for (int i = i0; i <= i1; ++i) {
        const int e0 = start[rowb + i + 1];
        for (int t = start[rowb + i]; t < e0; ++t) {
          const float2 pp = sorted[pb + t];
          const float dx = qp.x - pp.x, dy = qp.y - pp.y;
          m = fminf(m, fmaf(dx, dx, dy * dy));
        }
      }
    }
    const int j0 = max(cj - k + 1, 0), j1 = min(cj + k - 1, GD - 1);
    if (lef) {
      for (int j = j0; j <= j1; ++j) {
        const int cb = soff + j * GD + (ci - k);
        const int e0 = start[cb + 1];
        for (int t = start[cb]; t < e0; ++t) {
          const float2 pp = sorted[pb + t];
          const float dx = qp.x - pp.x, dy = qp.y - pp.y;
          m = fminf(m, fmaf(dx, dx, dy * dy));
        }
      }
    }
    if (rig) {
      for (int j = j0; j <= j1; ++j) {
        const int cb = soff + j * GD + (ci + k);
        const int e0 = start[cb + 1];
        for (int t = start[cb]; t < e0; ++t) {
          const float2 pp = sorted[pb + t];
          const float dx = qp.x - pp.x, dy = qp.y - pp.y;
          m = fminf(m, fmaf(dx, dx, dy * dy));
        }
      }
    }
  }

  float s = sqrtf(m + EPS);
#pragma unroll
  for (int off = 32; off > 0; off >>= 1)
    s += __shfl_down(s, off, 64);
  __shared__ float wsum[4];
  if ((threadIdx.x & 63) == 0) wsum[threadIdx.x >> 6] = s;
  __syncthreads();
  if (threadIdx.x == 0)
    partial[blk] = wsum[0] + wsum[1] + wsum[2] + wsum[3];
}

// Final: reduce 512 partials, scale, write scalar.
__global__ __launch_bounds__(512) void chamfer_final_kernel(
    const float* __restrict__ partial, float* __restrict__ out) {
  float v = partial[threadIdx.x];
#pragma unroll
  for (int off = 32; off > 0; off >>= 1)
    v += __shfl_down(v, off, 64);
  __shared__ float wsum[8];
  if ((threadIdx.x & 63) == 0) wsum[threadIdx.x >> 6] = v;
  __syncthreads();
  if (threadIdx.x == 0) {
    float s = 0.f;
#pragma unroll
    for (int i = 0; i < 8; ++i) s += wsum[i];
    out[0] = s * (1.0f / (float)(B * N));
  }
}

extern "C" void kernel_launch(void* const* d_in, const int* in_sizes, int n_in,
                              void* d_out, int out_size, void* d_ws, size_t ws_size,
                              hipStream_t stream) {
  const float* pred   = (const float*)d_in[0];
  const float* target = (const float*)d_in[1];
  float* out = (float*)d_out;

  float*  base    = (float*)d_ws;
  float*  bounds  = base;                         // 256 f32
  int*    start   = (int*)(base + 256);           // 64*257 ints
  float2* sorted  = (float2*)(base + 16704);      // 64*2048 float2
  float*  partial = base + 16704 + 262144;        // 512 f32

  build_grid_kernel<<<64, 256, 0, stream>>>(pred, target, bounds, start, sorted);
  query_kernel<<<512, 256, 0, stream>>>(pred, target, bounds, start, sorted, partial);
  chamfer_final_kernel<<<1, 512, 0, stream>>>(partial, out);
}